// Round 2
// baseline (801.121 us; speedup 1.0000x reference)
//
#include <hip/hip_runtime.h>

#define MULV 32
#define BASE 9
#define ROW 288      // MULV*BASE
#define NPATH 11
#define W3J_SZ 729   // 9*9*9
#define PACK_STRIDE 384  // 363 packed coeffs per u, padded for alignment

// Path table: (i1,i2,io) blocks for IRREPS [(0,e),(1,o),(2,e)], dims {1,3,5}, offs {0,1,4}
// Blocks are disjoint cells of the 9x9x9 cube; values read from input w3j at runtime.
__device__ constexpr int p_o1[NPATH] = {0,1,4, 0,1,1,4, 0,1,4,4};
__device__ constexpr int p_d1[NPATH] = {1,3,5, 1,3,3,5, 1,3,5,5};
__device__ constexpr int p_o2[NPATH] = {0,1,4, 1,0,4,1, 4,1,0,4};
__device__ constexpr int p_d2[NPATH] = {1,3,5, 3,1,5,3, 5,3,1,5};
__device__ constexpr int p_o3[NPATH] = {0,0,0, 1,1,1,1, 4,4,4,4};
__device__ constexpr int p_d3[NPATH] = {1,1,1, 3,3,3,3, 5,5,5,5};
// running offset of each path's block in the packed coeff array (vol = d1*d2*d3)
__device__ constexpr int voloff[NPATH + 1] = {0,1,10,35,44,53,98,143,168,213,238,363};

__global__ void zero_ws_kernel(float* __restrict__ x2s, const int* __restrict__ dN) {
    long total4 = (long)dN[0] * (ROW / 4);
    long stride = (long)gridDim.x * blockDim.x;
    float4 z = make_float4(0.f, 0.f, 0.f, 0.f);
    for (long i = (long)blockIdx.x * blockDim.x + threadIdx.x; i < total4; i += stride)
        ((float4*)x2s)[i] = z;
}

// packed[u][pos] = weights[u,p] * w3j[p, cell(pos)]  (path blocks are disjoint)
__global__ void ww_build_kernel(const float* __restrict__ weights,
                                const float* __restrict__ w3j,
                                float* __restrict__ packed) {
    int u = blockIdx.x;
    for (int t = threadIdx.x; t < 363; t += blockDim.x) {
        int p = 0;
        while (t >= voloff[p + 1]) ++p;
        int local = t - voloff[p];
        int d2 = p_d2[p], d3 = p_d3[p];
        int k = local % d3;
        int j = (local / d3) % d2;
        int i = local / (d3 * d2);
        int idx = (p_o1[p] + i) * 81 + (p_o2[p] + j) * 9 + (p_o3[p] + k);
        packed[u * PACK_STRIDE + t] = weights[u * NPATH + p] * w3j[p * W3J_SZ + idx];
    }
}

__global__ void scatter_add_kernel(const float* __restrict__ x2,
                                   const int* __restrict__ idxs,
                                   float* __restrict__ x2s, int E) {
    long t = (long)blockIdx.x * blockDim.x + threadIdx.x;   // over E * 72 float4s
    long total = (long)E * (ROW / 4);
    if (t >= total) return;
    int e = (int)(t / (ROW / 4));
    int c4 = (int)(t - (long)e * (ROW / 4));
    float4 v = ((const float4*)x2)[t];                      // coalesced: index == t
    float* dst = x2s + (long)idxs[e] * ROW + c4 * 4;
    atomicAdd(dst + 0, v.x);
    atomicAdd(dst + 1, v.y);
    atomicAdd(dst + 2, v.z);
    atomicAdd(dst + 3, v.w);
}

__global__ __launch_bounds__(256) void contract_kernel(
    const float* __restrict__ x1, const int* __restrict__ idxs,
    const float* __restrict__ x2s, const float* __restrict__ wwp,
    float* __restrict__ out, int E)
{
    const int u = blockIdx.x;                       // 0..31 — block-uniform
    const long e = (long)blockIdx.y * 256 + threadIdx.x;
    if (e >= (long)E) return;

    const float* __restrict__ wp = wwp + u * PACK_STRIDE;   // uniform base -> s_load
    const float* __restrict__ p1 = x1 + e * ROW + u * BASE;
    const int n = idxs[e];
    const float* __restrict__ p2 = x2s + (long)n * ROW + u * BASE;

    float x1v[BASE], x2v[BASE], acc[BASE];
    #pragma unroll
    for (int i = 0; i < BASE; ++i) {
        x1v[i] = p1[i];
        x2v[i] = p2[i];
        acc[i] = 0.0f;
    }

    #pragma unroll
    for (int p = 0; p < NPATH; ++p) {
        #pragma unroll
        for (int i = 0; i < p_d1[p]; ++i) {
            #pragma unroll
            for (int j = 0; j < p_d2[p]; ++j) {
                float xx = x1v[p_o1[p] + i] * x2v[p_o2[p] + j];
                #pragma unroll
                for (int k = 0; k < p_d3[p]; ++k) {
                    float w = wp[voloff[p] + (i * p_d2[p] + j) * p_d3[p] + k];
                    acc[p_o3[p] + k] = fmaf(w, xx, acc[p_o3[p] + k]);
                }
            }
        }
    }

    float* __restrict__ po = out + e * ROW + u * BASE;
    #pragma unroll
    for (int k = 0; k < BASE; ++k) po[k] = acc[k];
}

extern "C" void kernel_launch(void* const* d_in, const int* in_sizes, int n_in,
                              void* d_out, int out_size, void* d_ws, size_t ws_size,
                              hipStream_t stream) {
    const float* x1      = (const float*)d_in[0];
    const float* x2      = (const float*)d_in[1];
    const int*   idxs    = (const int*)d_in[2];
    const float* weights = (const float*)d_in[3];
    const float* w3j     = (const float*)d_in[4];
    const int*   dN      = (const int*)d_in[5];
    float* out = (float*)d_out;

    float* packed = (float*)d_ws;                         // [32, PACK_STRIDE]
    float* x2s    = (float*)d_ws + MULV * PACK_STRIDE;    // [N, ROW]

    const int E = in_sizes[2];

    // 1) zero the node accumulator (N known only on device)
    zero_ws_kernel<<<1024, 256, 0, stream>>>(x2s, dN);

    // 2) build packed per-u coefficients
    ww_build_kernel<<<MULV, 256, 0, stream>>>(weights, w3j, packed);

    // 3) scatter-add edges -> nodes (float4 loads, 4 atomics each)
    long total4 = (long)E * (ROW / 4);
    int sblocks = (int)((total4 + 255) / 256);
    scatter_add_kernel<<<sblocks, 256, 0, stream>>>(x2, idxs, x2s, E);

    // 4) gather + contraction; u in grid.x so all u-slices of an edge range are
    //    time-adjacent (L2/L3 reuse of the strided x1/out lines)
    dim3 grid(MULV, (unsigned)((E + 255) / 256));
    contract_kernel<<<grid, 256, 0, stream>>>(x1, idxs, x2s, packed, out, E);
}

// Round 3
// 349.919 us; speedup vs baseline: 2.2894x; 2.2894x over previous
//
#include <hip/hip_runtime.h>

#define MULV 32
#define BASE 9
#define ROW 288          // MULV*BASE
#define NPATH 11
#define W3J_SZ 729       // 9*9*9
#define PACK_STRIDE 384  // 363 packed coeffs per u, padded
#define PACK_TOTAL (MULV * PACK_STRIDE)   // 12288 floats

// Path table: (i1,i2,io) blocks for IRREPS [(0,e),(1,o),(2,e)], dims {1,3,5}, offs {0,1,4}
// Blocks are disjoint cells of the 9x9x9 cube; values read from input w3j at runtime.
__device__ constexpr int p_o1[NPATH] = {0,1,4, 0,1,1,4, 0,1,4,4};
__device__ constexpr int p_d1[NPATH] = {1,3,5, 1,3,3,5, 1,3,5,5};
__device__ constexpr int p_o2[NPATH] = {0,1,4, 1,0,4,1, 4,1,0,4};
__device__ constexpr int p_d2[NPATH] = {1,3,5, 3,1,5,3, 5,3,1,5};
__device__ constexpr int p_o3[NPATH] = {0,0,0, 1,1,1,1, 4,4,4,4};
__device__ constexpr int p_d3[NPATH] = {1,1,1, 3,3,3,3, 5,5,5,5};
__device__ constexpr int voloff[NPATH + 1] = {0,1,10,35,44,53,98,143,168,213,238,363};

// ---- ws layout (device-side pointer math; only N comes from device) ----
// packed : ws[0 .. PACK_TOTAL)                     (12288 floats = 48 KiB)
// x2s    : ws + PACK_TOTAL, N*ROW floats
// count  : (int*) after x2s, N ints
// offset : count + N
// cursor : count + 2N
// bucket : count + 3N, E ints

__global__ void zero_count_kernel(float* __restrict__ ws, const int* __restrict__ dN) {
    int N = dN[0];
    int* count = (int*)(ws + PACK_TOTAL + (long)N * ROW);
    for (int i = blockIdx.x * blockDim.x + threadIdx.x; i < N; i += gridDim.x * blockDim.x)
        count[i] = 0;
}

__global__ void hist_kernel(const int* __restrict__ idxs, float* __restrict__ ws,
                            const int* __restrict__ dN, int E) {
    int N = dN[0];
    int* count = (int*)(ws + PACK_TOTAL + (long)N * ROW);
    int t = blockIdx.x * blockDim.x + threadIdx.x;
    if (t < E) atomicAdd(&count[idxs[t]], 1);
}

// single-block exclusive scan: offset[i] = sum count[0..i); also copy to cursor
__global__ void scan_kernel(float* __restrict__ ws, const int* __restrict__ dN) {
    int N = dN[0];
    int* count  = (int*)(ws + PACK_TOTAL + (long)N * ROW);
    int* offset = count + N;
    int* cursor = count + 2 * N;
    __shared__ int buf[1024];
    __shared__ int carry_s;
    if (threadIdx.x == 0) carry_s = 0;
    __syncthreads();
    for (int base = 0; base < N; base += 1024) {
        int i = base + (int)threadIdx.x;
        int v = (i < N) ? count[i] : 0;
        buf[threadIdx.x] = v;
        __syncthreads();
        #pragma unroll
        for (int off = 1; off < 1024; off <<= 1) {
            int t = (threadIdx.x >= off) ? buf[threadIdx.x - off] : 0;
            __syncthreads();
            buf[threadIdx.x] += t;
            __syncthreads();
        }
        int excl = carry_s + buf[threadIdx.x] - v;
        if (i < N) { offset[i] = excl; cursor[i] = excl; }
        __syncthreads();
        if (threadIdx.x == 0) carry_s += buf[1023];
        __syncthreads();
    }
}

__global__ void fill_kernel(const int* __restrict__ idxs, float* __restrict__ ws,
                            const int* __restrict__ dN, int E) {
    int N = dN[0];
    int* count  = (int*)(ws + PACK_TOTAL + (long)N * ROW);
    int* cursor = count + 2 * N;
    int* bucket = count + 3 * N;
    int t = blockIdx.x * blockDim.x + threadIdx.x;
    if (t < E) {
        int n = idxs[t];
        int pos = atomicAdd(&cursor[n], 1);
        bucket[pos] = t;
    }
}

// one wave per node: x2s[n,:] = sum over edges in bucket of x2[e,:]
__global__ __launch_bounds__(256) void gather_sum_kernel(const float* __restrict__ x2,
                                                         float* __restrict__ ws,
                                                         const int* __restrict__ dN) {
    int N = dN[0];
    float* x2s  = ws + PACK_TOTAL;
    int* count  = (int*)(x2s + (long)N * ROW);
    int* offset = count + N;
    int* bucket = count + 3 * N;
    const int lane = threadIdx.x & 63;
    const int wv   = threadIdx.x >> 6;
    for (int n0 = blockIdx.x * 4 + wv; n0 < N; n0 += gridDim.x * 4) {
        int n   = __builtin_amdgcn_readfirstlane(n0);
        int off = offset[n];
        int deg = count[n];
        float4 a0 = make_float4(0.f, 0.f, 0.f, 0.f);
        float4 a1 = make_float4(0.f, 0.f, 0.f, 0.f);
        for (int d = 0; d < deg; ++d) {
            int e = bucket[off + d];
            const float4* row = (const float4*)(x2 + (long)e * ROW);
            float4 v = row[lane];
            a0.x += v.x; a0.y += v.y; a0.z += v.z; a0.w += v.w;
            if (lane < 8) {
                float4 w = row[64 + lane];
                a1.x += w.x; a1.y += w.y; a1.z += w.z; a1.w += w.w;
            }
        }
        float4* orow = (float4*)(x2s + (long)n * ROW);
        orow[lane] = a0;
        if (lane < 8) orow[64 + lane] = a1;
    }
}

// packed[u][pos] = weights[u,p] * w3j[p, cell(pos)]
__global__ void ww_build_kernel(const float* __restrict__ weights,
                                const float* __restrict__ w3j,
                                float* __restrict__ packed) {
    int u = blockIdx.x;
    for (int t = threadIdx.x; t < 363; t += blockDim.x) {
        int p = 0;
        while (t >= voloff[p + 1]) ++p;
        int local = t - voloff[p];
        int d2 = p_d2[p], d3 = p_d3[p];
        int k = local % d3;
        int j = (local / d3) % d2;
        int i = local / (d3 * d2);
        int idx = (p_o1[p] + i) * 81 + (p_o2[p] + j) * 9 + (p_o3[p] + k);
        packed[u * PACK_STRIDE + t] = weights[u * NPATH + p] * w3j[p * W3J_SZ + idx];
    }
}

// one thread = one edge, u-loop inside (coeffs stay wave-uniform -> s_load;
// per-row accesses walk sequentially -> L1 line reuse)
__global__ __launch_bounds__(256) void contract_kernel(
    const float* __restrict__ x1, const int* __restrict__ idxs,
    const float* __restrict__ ws, float* __restrict__ out, int E)
{
    long e = (long)blockIdx.x * 256 + threadIdx.x;
    if (e >= (long)E) return;
    const float* __restrict__ packed = ws;
    const float* __restrict__ x2s    = ws + PACK_TOTAL;
    const float* __restrict__ r1 = x1 + e * ROW;
    const float* __restrict__ r2 = x2s + (long)idxs[e] * ROW;
    float* __restrict__ ro = out + e * ROW;

    #pragma unroll 1
    for (int u = 0; u < MULV; ++u) {
        const float* __restrict__ wp = packed + u * PACK_STRIDE;  // uniform -> s_load
        float x1v[BASE], x2v[BASE], acc[BASE];
        #pragma unroll
        for (int i = 0; i < BASE; ++i) {
            x1v[i] = r1[u * BASE + i];
            x2v[i] = r2[u * BASE + i];
            acc[i] = 0.0f;
        }
        #pragma unroll
        for (int p = 0; p < NPATH; ++p) {
            #pragma unroll
            for (int i = 0; i < p_d1[p]; ++i) {
                #pragma unroll
                for (int j = 0; j < p_d2[p]; ++j) {
                    float xx = x1v[p_o1[p] + i] * x2v[p_o2[p] + j];
                    #pragma unroll
                    for (int k = 0; k < p_d3[p]; ++k) {
                        float w = wp[voloff[p] + (i * p_d2[p] + j) * p_d3[p] + k];
                        acc[p_o3[p] + k] = fmaf(w, xx, acc[p_o3[p] + k]);
                    }
                }
            }
        }
        #pragma unroll
        for (int k = 0; k < BASE; ++k) ro[u * BASE + k] = acc[k];
    }
}

extern "C" void kernel_launch(void* const* d_in, const int* in_sizes, int n_in,
                              void* d_out, int out_size, void* d_ws, size_t ws_size,
                              hipStream_t stream) {
    const float* x1      = (const float*)d_in[0];
    const float* x2      = (const float*)d_in[1];
    const int*   idxs    = (const int*)d_in[2];
    const float* weights = (const float*)d_in[3];
    const float* w3j     = (const float*)d_in[4];
    const int*   dN      = (const int*)d_in[5];
    float* out = (float*)d_out;
    float* ws  = (float*)d_ws;

    const int E = in_sizes[2];
    const int eb = (E + 255) / 256;

    // CSR build: count -> scan -> bucket fill
    zero_count_kernel<<<256, 256, 0, stream>>>(ws, dN);
    hist_kernel<<<eb, 256, 0, stream>>>(idxs, ws, dN, E);
    scan_kernel<<<1, 1024, 0, stream>>>(ws, dN);
    fill_kernel<<<eb, 256, 0, stream>>>(idxs, ws, dN, E);

    // per-node gather-sum (replaces 37.7M-atomic scatter)
    gather_sum_kernel<<<2048, 256, 0, stream>>>(x2, ws, dN);

    // packed per-u coefficients
    ww_build_kernel<<<MULV, 256, 0, stream>>>(weights, w3j, ws);

    // contraction: thread = edge, u-loop inside
    contract_kernel<<<eb, 256, 0, stream>>>(x1, idxs, ws, out, E);
}